// Round 3
// baseline (194.048 us; speedup 1.0000x reference)
//
#include <hip/hip_runtime.h>

// FractionalDerivative: out[b,c,t] = sum_{k=0}^{K-1} w[c,k] * x[b,c,t-k]
// w_0 = 1, w_k = w_{k-1} * (k-1-a)/k, a = clip(alpha[c], 0.01, 1.99)
// x: (16, 512, 8192) fp32.
// R2: thread-contiguous spans. Each thread owns 32 floats, issues 11
// independent float4 loads up front (3 halo + 8 own, zero inter-thread
// redundancy), slides the window in registers, stores 8 float4s.
// Attacks the R0/R1 limiter: per-wave MLP was 4 dependent-bounded loads/iter
// with 4x redundant L1 traffic -> ~67 cyc/VMEM-instr effective.

constexpr int K = 10;
constexpr int T = 8192;
constexpr int C = 512;
constexpr int PT = 32;            // floats per thread (contiguous)
constexpr int NJ = PT / 4;        // 8 output float4 blocks per thread
constexpr int NF = NJ + 3;        // 11 input float4s (3 halo + 8 own)

__global__ __launch_bounds__(256) void frac_deriv_kernel(
    const float* __restrict__ x,
    const float* __restrict__ alpha,
    float* __restrict__ out) {
    const int row = blockIdx.x;          // row = b*C + c, one block per row
    const int c = row & (C - 1);

    // Per-channel GL weights (block-uniform, hoisted)
    float a = alpha[c];
    a = fminf(fmaxf(a, 0.01f), 1.99f);
    float w[K];
    w[0] = 1.0f;
#pragma unroll
    for (int k = 1; k < K; ++k) {
        w[k] = w[k - 1] * ((float)k - 1.0f - a) / (float)k;
    }

    const float* xr   = x   + (size_t)row * T;
    float*       outr = out + (size_t)row * T;
    const int base = (int)threadIdx.x * PT;   // this thread's span start

    // Issue all 11 independent loads up front (max MLP).
    // f[i] covers x[base - 12 + 4*i .. base - 9 + 4*i], i = 0..10.
    // For i >= 3 the address is always >= base >= 0 (guard folds away);
    // only thread 0's i < 3 loads are zero-filled.
    float4 f[NF];
#pragma unroll
    for (int i = 0; i < NF; ++i) {
        const int tb = base - 12 + 4 * i;
        if (tb >= 0) {
            f[i] = *reinterpret_cast<const float4*>(xr + tb);
        } else {
            f[i] = make_float4(0.f, 0.f, 0.f, 0.f);
        }
    }

    // Slide: output block j (t = base+4j .. base+4j+3) consumes f[j..j+3].
#pragma unroll
    for (int j = 0; j < NJ; ++j) {
        float xa[16];
        xa[0]  = f[j].x;     xa[1]  = f[j].y;     xa[2]  = f[j].z;     xa[3]  = f[j].w;
        xa[4]  = f[j + 1].x; xa[5]  = f[j + 1].y; xa[6]  = f[j + 1].z; xa[7]  = f[j + 1].w;
        xa[8]  = f[j + 2].x; xa[9]  = f[j + 2].y; xa[10] = f[j + 2].z; xa[11] = f[j + 2].w;
        xa[12] = f[j + 3].x; xa[13] = f[j + 3].y; xa[14] = f[j + 3].z; xa[15] = f[j + 3].w;

        float o[4];
#pragma unroll
        for (int i = 0; i < 4; ++i) {
            float acc = 0.0f;
#pragma unroll
            for (int k = 0; k < K; ++k) {
                acc = fmaf(w[k], xa[12 + i - k], acc);
            }
            o[i] = acc;
        }
        *reinterpret_cast<float4*>(outr + base + 4 * j) =
            make_float4(o[0], o[1], o[2], o[3]);
    }
}

extern "C" void kernel_launch(void* const* d_in, const int* in_sizes, int n_in,
                              void* d_out, int out_size, void* d_ws, size_t ws_size,
                              hipStream_t stream) {
    const float* x     = (const float*)d_in[0];
    const float* alpha = (const float*)d_in[1];
    float*       out   = (float*)d_out;

    const int nrows = in_sizes[0] / T;  // B*C = 8192 rows
    frac_deriv_kernel<<<nrows, 256, 0, stream>>>(x, alpha, out);
}

// Round 5
// 98.101 us; speedup vs baseline: 1.9780x; 1.9780x over previous
//
#include <hip/hip_runtime.h>

// FractionalDerivative: out[b,c,t] = sum_{k=0}^{K-1} w[c,k] * x[b,c,t-k]
// w_0 = 1, w_k = w_{k-1} * (k-1-a)/k, a = clip(alpha[c], 0.01, 1.99)
// x: (16, 512, 8192) fp32.
// R4: R3 structure (async global->LDS staging, 16B global_load_lds) with the
// halo bug fixed: R3's single 16-BYTE async copy only filled 4 of the 16 halo
// FLOATS, leaving x[s-12..s-1] uninitialized on interior tiles. Halo now uses
// a plain 16-thread scalar path (trivially correct, 64 B per block).

constexpr int K = 10;
constexpr int T = 8192;
constexpr int C = 512;
constexpr int TILE = 4096;            // outputs per block
constexpr int HALO = 16;              // lds floats before tile start (12 used)
constexpr int LDSF = TILE + HALO;     // 4112 floats = 16448 B
constexpr int NSTG = TILE / 4 / 256;  // 4 async 16B loads per thread
constexpr int NCMP = TILE / 4 / 256;  // 4 output float4s per thread

__device__ __forceinline__ void async_copy16(const float* g, float* l) {
    __builtin_amdgcn_global_load_lds(
        (const __attribute__((address_space(1))) void*)g,
        (__attribute__((address_space(3))) void*)l, 16, 0, 0);
}

__global__ __launch_bounds__(256) void frac_deriv_kernel(
    const float* __restrict__ x,
    const float* __restrict__ alpha,
    float* __restrict__ out) {
    __shared__ float lds[LDSF];       // lds[i] = x[s - HALO + i]

    const int bid  = blockIdx.x;
    const int row  = bid >> 1;        // row = b*C + c
    const int tile = bid & 1;
    const int c    = row & (C - 1);
    const int s    = tile * TILE;     // tile start in t
    const int tid  = (int)threadIdx.x;

    // Per-channel GL weights (block-uniform, hoisted)
    float a = fminf(fmaxf(alpha[c], 0.01f), 1.99f);
    float w[K];
    w[0] = 1.0f;
#pragma unroll
    for (int k = 1; k < K; ++k) {
        w[k] = w[k - 1] * ((float)k - 1.0f - a) / (float)k;
    }

    const float* xr   = x   + (size_t)row * T;
    float*       outr = out + (size_t)row * T;

    // ---- Stage: 4 async 16B loads per thread, wave-linear LDS dest ----
    // Per wave w, iter i: lane l's dest byte = HALO*4 + (i*256 + w*64 + l)*16
    // = uniform base + l*16 -> the legal global_load_lds layout (m104).
#pragma unroll
    for (int i = 0; i < NSTG; ++i) {
        const int f = (i * 256 + tid) * 4;       // float idx within tile
        async_copy16(xr + s + f, &lds[HALO + f]);
    }
    // Halo: lds[0..15] = x[s-16 .. s-1], zero for t < 0. Plain scalar path
    // (16 floats/block) — trivially correct, negligible traffic.
    if (tid < HALO) {
        lds[tid] = (s > 0) ? xr[s - HALO + tid] : 0.0f;
    }
    __syncthreads();  // drains vmcnt(0) + lgkmcnt(0) before barrier

    // ---- Compute: windows from LDS, conflict-free lane-linear b128 ----
#pragma unroll
    for (int j = 0; j < NCMP; ++j) {
        const int tf = (j * 256 + tid) * 4;      // output offset within tile
        // window x[s+tf-12 .. s+tf+3] == lds[tf+4 .. tf+19], 16B-aligned
        const float4* wp = reinterpret_cast<const float4*>(&lds[tf + 4]);
        const float4 f0 = wp[0];
        const float4 f1 = wp[1];
        const float4 f2 = wp[2];
        const float4 f3 = wp[3];
        float xa[16];
        xa[0]  = f0.x; xa[1]  = f0.y; xa[2]  = f0.z; xa[3]  = f0.w;
        xa[4]  = f1.x; xa[5]  = f1.y; xa[6]  = f1.z; xa[7]  = f1.w;
        xa[8]  = f2.x; xa[9]  = f2.y; xa[10] = f2.z; xa[11] = f2.w;
        xa[12] = f3.x; xa[13] = f3.y; xa[14] = f3.z; xa[15] = f3.w;

        float o[4];
#pragma unroll
        for (int i = 0; i < 4; ++i) {
            float acc = 0.0f;
#pragma unroll
            for (int k = 0; k < K; ++k) {
                acc = fmaf(w[k], xa[12 + i - k], acc);
            }
            o[i] = acc;
        }
        *reinterpret_cast<float4*>(outr + s + tf) =
            make_float4(o[0], o[1], o[2], o[3]);
    }
}

extern "C" void kernel_launch(void* const* d_in, const int* in_sizes, int n_in,
                              void* d_out, int out_size, void* d_ws, size_t ws_size,
                              hipStream_t stream) {
    const float* x     = (const float*)d_in[0];
    const float* alpha = (const float*)d_in[1];
    float*       out   = (float*)d_out;

    const int nrows  = in_sizes[0] / T;          // B*C = 8192 rows
    const int nblk   = nrows * (T / TILE);       // 16384 blocks
    frac_deriv_kernel<<<nblk, 256, 0, stream>>>(x, alpha, out);
}

// Round 6
// 86.341 us; speedup vs baseline: 2.2475x; 1.1362x over previous
//
#include <hip/hip_runtime.h>

// FractionalDerivative: out[b,c,t] = sum_{k=0}^{K-1} w[c,k] * x[b,c,t-k]
// w_0 = 1, w_k = w_{k-1} * (k-1-a)/k, a = clip(alpha[c], 0.01, 1.99)
// x: (16, 512, 8192) fp32.
// R5: R4 (async global->LDS staging, 98 us) + NON-TEMPORAL output stores.
// Rationale: output stream (256 MiB) allocates in L2/L3 and evicts x
// (256 MiB, marginal L3 fit) -> ~140-170 MB of x re-fetched from HBM each
// replay. nt stores stream the output past L3, letting it retain x.

constexpr int K = 10;
constexpr int T = 8192;
constexpr int C = 512;
constexpr int TILE = 4096;            // outputs per block
constexpr int HALO = 16;              // lds floats before tile start (12 used)
constexpr int LDSF = TILE + HALO;     // 4112 floats = 16448 B
constexpr int NSTG = TILE / 4 / 256;  // 4 async 16B loads per thread
constexpr int NCMP = TILE / 4 / 256;  // 4 output float4s per thread

typedef float f32x4 __attribute__((ext_vector_type(4)));

__device__ __forceinline__ void async_copy16(const float* g, float* l) {
    __builtin_amdgcn_global_load_lds(
        (const __attribute__((address_space(1))) void*)g,
        (__attribute__((address_space(3))) void*)l, 16, 0, 0);
}

__global__ __launch_bounds__(256) void frac_deriv_kernel(
    const float* __restrict__ x,
    const float* __restrict__ alpha,
    float* __restrict__ out) {
    __shared__ float lds[LDSF];       // lds[i] = x[s - HALO + i]

    const int bid  = blockIdx.x;
    const int row  = bid >> 1;        // row = b*C + c
    const int tile = bid & 1;
    const int c    = row & (C - 1);
    const int s    = tile * TILE;     // tile start in t
    const int tid  = (int)threadIdx.x;

    // Per-channel GL weights (block-uniform, hoisted)
    float a = fminf(fmaxf(alpha[c], 0.01f), 1.99f);
    float w[K];
    w[0] = 1.0f;
#pragma unroll
    for (int k = 1; k < K; ++k) {
        w[k] = w[k - 1] * ((float)k - 1.0f - a) / (float)k;
    }

    const float* xr   = x   + (size_t)row * T;
    float*       outr = out + (size_t)row * T;

    // ---- Stage: 4 async 16B loads per thread, wave-linear LDS dest ----
#pragma unroll
    for (int i = 0; i < NSTG; ++i) {
        const int f = (i * 256 + tid) * 4;       // float idx within tile
        async_copy16(xr + s + f, &lds[HALO + f]);
    }
    // Halo: lds[0..15] = x[s-16 .. s-1], zero for t < 0.
    if (tid < HALO) {
        lds[tid] = (s > 0) ? xr[s - HALO + tid] : 0.0f;
    }
    __syncthreads();  // drains vmcnt(0) + lgkmcnt(0) before barrier

    // ---- Compute: windows from LDS, conflict-free lane-linear b128 ----
#pragma unroll
    for (int j = 0; j < NCMP; ++j) {
        const int tf = (j * 256 + tid) * 4;      // output offset within tile
        // window x[s+tf-12 .. s+tf+3] == lds[tf+4 .. tf+19], 16B-aligned
        const float4* wp = reinterpret_cast<const float4*>(&lds[tf + 4]);
        const float4 f0 = wp[0];
        const float4 f1 = wp[1];
        const float4 f2 = wp[2];
        const float4 f3 = wp[3];
        float xa[16];
        xa[0]  = f0.x; xa[1]  = f0.y; xa[2]  = f0.z; xa[3]  = f0.w;
        xa[4]  = f1.x; xa[5]  = f1.y; xa[6]  = f1.z; xa[7]  = f1.w;
        xa[8]  = f2.x; xa[9]  = f2.y; xa[10] = f2.z; xa[11] = f2.w;
        xa[12] = f3.x; xa[13] = f3.y; xa[14] = f3.z; xa[15] = f3.w;

        float o[4];
#pragma unroll
        for (int i = 0; i < 4; ++i) {
            float acc = 0.0f;
#pragma unroll
            for (int k = 0; k < K; ++k) {
                acc = fmaf(w[k], xa[12 + i - k], acc);
            }
            o[i] = acc;
        }
        f32x4 v = {o[0], o[1], o[2], o[3]};
        __builtin_nontemporal_store(
            v, reinterpret_cast<f32x4*>(outr + s + tf));
    }
}

extern "C" void kernel_launch(void* const* d_in, const int* in_sizes, int n_in,
                              void* d_out, int out_size, void* d_ws, size_t ws_size,
                              hipStream_t stream) {
    const float* x     = (const float*)d_in[0];
    const float* alpha = (const float*)d_in[1];
    float*       out   = (float*)d_out;

    const int nrows  = in_sizes[0] / T;          // B*C = 8192 rows
    const int nblk   = nrows * (T / TILE);       // 16384 blocks
    frac_deriv_kernel<<<nblk, 256, 0, stream>>>(x, alpha, out);
}